// Round 20
// baseline (859.801 us; speedup 1.0000x reference)
//
#include <hip/hip_runtime.h>

#define M_DIM 65536
#define K_DIM 2048
#define N_DIM 1024
#define EPSV 1e-5f

typedef __bf16 bf16;
typedef bf16 bf16x8 __attribute__((ext_vector_type(8)));
typedef bf16 bf16x4 __attribute__((ext_vector_type(4)));
typedef float f32x4 __attribute__((ext_vector_type(4)));

// monotone float <-> uint encoding for atomicMin on float
__device__ inline unsigned fenc(float f) {
    unsigned u = __float_as_uint(f);
    return (u & 0x80000000u) ? ~u : (u | 0x80000000u);
}
__device__ inline float fdec(unsigned e) {
    unsigned u = (e & 0x80000000u) ? (e & 0x7fffffffu) : ~e;
    return __uint_as_float(u);
}

__device__ __forceinline__ void gload_lds16(const bf16* g, bf16* l) {
    __builtin_amdgcn_global_load_lds(
        (const __attribute__((address_space(1))) unsigned int*)g,
        (__attribute__((address_space(3))) unsigned int*)l, 16, 0, 0);
}

// fp32 -> bf16 conversion (W only: 4 MB, ~2 us)
__global__ void cvt_kernel(const float* __restrict__ in, bf16* __restrict__ out, long n4) {
    long i = (long)blockIdx.x * blockDim.x + threadIdx.x;
    long stride = (long)gridDim.x * blockDim.x;
    for (; i < n4; i += stride) {
        f32x4 v = ((const f32x4*)in)[i];
        bf16x4 h;
        h[0] = (bf16)v[0]; h[1] = (bf16)v[1]; h[2] = (bf16)v[2]; h[3] = (bf16)v[3];
        ((bf16x4*)out)[i] = h;
    }
}

// R19 + 4-blocks/CU. 128x128, BK=64, 4 waves, 32 KB LDS, conflict-free
// XOR swizzle, XCD swizzle, A staged from FP32 x with full-iteration
// register prefetch and an exact vmcnt ledger:
//   [B: 4x gload_lds] sched_barrier(0) [cvt va -> swizzled ds_write]
//   [A_PREFETCH(kt+1): 8 loads] barrier-1: vmcnt(8)+lgkm(0) [MFMA]
//   barrier-2: lgkm(0) only (prefetch survives; consumed next iter).
// R19 measured: VGPR 80, WRITE 16 MB (no spill), occupancy 31.5%,
// GEMM 433 us. VGPR 80 << 128 = the 4-waves/EU cap, so the only thing
// stopping a 4th resident block was launch_bounds(256,3). Bump to 4:
// one more independent block per CU to cover the cvt/VMEM windows
// (the m114/R13 cross-block mechanism — the session's one reliable lever).
__global__ __launch_bounds__(256, 4)
void gemm_fused(const float* __restrict__ X, const bf16* __restrict__ Wb,
                const float* __restrict__ gnw, const float* __restrict__ gnb,
                unsigned* __restrict__ rowmin) {
    __shared__ __align__(16) bf16 As[128][64];
    __shared__ __align__(16) bf16 Bs[128][64];

    const int tid = threadIdx.x;
    const int wave = tid >> 6, lane = tid & 63;
    const int wr = wave >> 1, wc = wave & 1;   // 2 x 2 wave grid
    const int q = lane >> 4, r = lane & 15;

    // T1: bijective XCD-chunked swizzle (4096 blocks % 8 == 0)
    const int bid = blockIdx.x;
    const int swz = (bid & 7) * 512 + (bid >> 3);
    const int bx = swz & 7, by = swz >> 3;
    const int brow = by * 128, bcol = bx * 128;

    const float* Arowf = X + (size_t)brow * K_DIM;
    const bf16* Brow = Wb + (size_t)bcol * K_DIM;

    f32x4 acc[4][4];
#pragma unroll
    for (int m = 0; m < 4; ++m)
#pragma unroll
        for (int n = 0; n < 4; ++n) acc[m][n] = 0.0f;

    // read-side swizzled granule offsets (bf16 units), per kk half
    const int r7 = r & 7;
    const int ga0 = ((0 + q) ^ r7) * 8;   // kk = 0
    const int ga1 = ((4 + q) ^ r7) * 8;   // kk = 32
    const int arow_l = wr * 64 + r;       // + m*16
    const int brow_l = wc * 64 + r;       // + n*16

    f32x4 va[8];  // single in-flight fp32 A buffer (statically indexed)

#define A_PREFETCH(KT) do {                                                       \
        const int kp = ((KT) & 31) * 64;                                          \
        _Pragma("unroll") for (int j = 0; j < 4; ++j) {                           \
            int gi = j * 256 + tid;                                               \
            int row = gi >> 3, g = gi & 7;                                        \
            const float* src = Arowf + (size_t)row * K_DIM + kp + g * 8;          \
            va[2 * j]     = *(const f32x4*)(src);                                 \
            va[2 * j + 1] = *(const f32x4*)(src + 4);                             \
        }                                                                         \
    } while (0)

#define TILE_ITER(KT) do {                                                        \
        const int k0 = (KT) * 64;                                                 \
        /* B: gload_lds + source-side swizzle (4 loads, MUST be oldest) */        \
        _Pragma("unroll") for (int i = 0; i < 4; ++i) {                           \
            int chunk = i * 256 + tid;                                            \
            int row = chunk >> 3, g = chunk & 7;                                  \
            int gsw = g ^ (row & 7);                                              \
            gload_lds16(Brow + (size_t)row * K_DIM + k0 + gsw * 8,                \
                        &Bs[0][0] + (size_t)(i * 256 + (tid & 192)) * 8);         \
        }                                                                         \
        __builtin_amdgcn_sched_barrier(0);  /* pin: B before A-prefetch */        \
        /* A: convert va (tile KT, loaded last iter) + swizzled ds_write */       \
        _Pragma("unroll") for (int j = 0; j < 4; ++j) {                           \
            int gi = j * 256 + tid;                                               \
            int row = gi >> 3, g = gi & 7;                                        \
            bf16x8 h;                                                             \
            h[0] = (bf16)va[2 * j][0];     h[1] = (bf16)va[2 * j][1];             \
            h[2] = (bf16)va[2 * j][2];     h[3] = (bf16)va[2 * j][3];             \
            h[4] = (bf16)va[2 * j + 1][0]; h[5] = (bf16)va[2 * j + 1][1];         \
            h[6] = (bf16)va[2 * j + 1][2]; h[7] = (bf16)va[2 * j + 1][3];         \
            *(bf16x8*)(&As[0][0] + (size_t)row * 64 +                             \
                       (size_t)(g ^ (row & 7)) * 8) = h;                          \
        }                                                                         \
        /* A-prefetch for tile KT+1 (8 loads, newer than B) */                    \
        A_PREFETCH((KT) + 1);                                                     \
        /* barrier-1: drain exactly B (oldest 4 of 12) + LDS writes */            \
        asm volatile("s_waitcnt vmcnt(8) lgkmcnt(0)" ::: "memory");               \
        __builtin_amdgcn_s_barrier();                                             \
        asm volatile("" ::: "memory");                                            \
        /* MFMA region */                                                         \
        _Pragma("unroll") for (int kk = 0; kk < 2; ++kk) {                        \
            const int ga = kk ? ga1 : ga0;                                        \
            bf16x8 a[4], b[4];                                                    \
            _Pragma("unroll") for (int m = 0; m < 4; ++m)                         \
                a[m] = *(const bf16x8*)(&As[0][0] + (arow_l + m * 16) * 64 + ga); \
            _Pragma("unroll") for (int n = 0; n < 4; ++n)                         \
                b[n] = *(const bf16x8*)(&Bs[0][0] + (brow_l + n * 16) * 64 + ga); \
            _Pragma("unroll") for (int m = 0; m < 4; ++m)                         \
                _Pragma("unroll") for (int n = 0; n < 4; ++n)                     \
                    acc[m][n] = __builtin_amdgcn_mfma_f32_16x16x32_bf16(          \
                        a[m], b[n], acc[m][n], 0, 0, 0);                          \
        }                                                                         \
        /* barrier-2: lgkm only — A-prefetch survives */                          \
        asm volatile("s_waitcnt lgkmcnt(0)" ::: "memory");                        \
        __builtin_amdgcn_s_barrier();                                             \
        asm volatile("" ::: "memory");                                            \
    } while (0)

    // ---- prologue: load tile 0's fp32 A into va ----
    A_PREFETCH(0);

    // ---- main loop: 32 K-tiles ----
    for (int kt = 0; kt < 32; ++kt) {
        TILE_ITER(kt);   // kt=31 prefetches tile 0 (unused)
    }

    // ---- fused epilogue: GroupNorm (group == wave's 64-col span) + row min ----
    float gw[4], gb[4];
#pragma unroll
    for (int n = 0; n < 4; ++n) {
        int col = bcol + wc * 64 + n * 16 + r;
        gw[n] = gnw[col];
        gb[n] = gnb[col];
    }
#pragma unroll
    for (int m = 0; m < 4; ++m) {
#pragma unroll
        for (int j = 0; j < 4; ++j) {
            float s = 0.f, ss = 0.f;
#pragma unroll
            for (int n = 0; n < 4; ++n) {
                float v = acc[m][n][j];
                s += v; ss += v * v;
            }
#pragma unroll
            for (int d = 1; d < 16; d <<= 1) {
                s += __shfl_xor(s, d);
                ss += __shfl_xor(ss, d);
            }
            float mean = s * (1.f / 64.f);
            float var = ss * (1.f / 64.f) - mean * mean;
            float rstd = rsqrtf(var + EPSV);
            float mn = 3.4e38f;
#pragma unroll
            for (int n = 0; n < 4; ++n) {
                float y = (acc[m][n][j] - mean) * rstd * gw[n] + gb[n];
                mn = fminf(mn, y);
            }
#pragma unroll
            for (int d = 1; d < 16; d <<= 1) mn = fminf(mn, __shfl_xor(mn, d));
            if (r == 0)
                atomicMin(&rowmin[brow + wr * 64 + m * 16 + q * 4 + j], fenc(mn));
        }
    }
}

// out[m][n] = dec(rowmin[m]) + bias[n]
__global__ void bcast_kernel(const unsigned* __restrict__ rowmin,
                             const float* __restrict__ bias,
                             float* __restrict__ out) {
    const long total4 = (long)M_DIM * N_DIM / 4;
    long i = (long)blockIdx.x * blockDim.x + threadIdx.x;
    long stride = (long)gridDim.x * blockDim.x;
    for (; i < total4; i += stride) {
        int mrow = (int)(i >> 8);  // N/4 = 256 float4 per row
        int n4 = (int)(i & 255);
        float rm = fdec(rowmin[mrow]);
        f32x4 b = ((const f32x4*)bias)[n4];
        f32x4 o;
        o[0] = rm + b[0]; o[1] = rm + b[1]; o[2] = rm + b[2]; o[3] = rm + b[3];
        ((f32x4*)out)[i] = o;
    }
}

extern "C" void kernel_launch(void* const* d_in, const int* in_sizes, int n_in,
                              void* d_out, int out_size, void* d_ws, size_t ws_size,
                              hipStream_t stream) {
    const float* x = (const float*)d_in[0];
    const float* w = (const float*)d_in[1];
    const float* gnw = (const float*)d_in[2];
    const float* gnb = (const float*)d_in[3];
    const float* bias = (const float*)d_in[4];

    unsigned char* ws = (unsigned char*)d_ws;
    unsigned* rowmin = (unsigned*)ws;                          // 256 KB
    bf16* wb = (bf16*)(ws + (size_t)M_DIM * 4);                // 4 MB

    (void)hipMemsetAsync(rowmin, 0xFF, (size_t)M_DIM * 4, stream);  // +inf in encoding
    cvt_kernel<<<512, 256, 0, stream>>>(w, wb, (long)N_DIM * K_DIM / 4);

    gemm_fused<<<dim3(4096), 256, 0, stream>>>(x, wb, gnw, gnb, rowmin);

    bcast_kernel<<<2048, 256, 0, stream>>>(rowmin, bias, (float*)d_out);
}

// Round 21
// 472.799 us; speedup vs baseline: 1.8185x; 1.8185x over previous
//
#include <hip/hip_runtime.h>

#define M_DIM 65536
#define K_DIM 2048
#define N_DIM 1024
#define EPSV 1e-5f

typedef __bf16 bf16;
typedef bf16 bf16x8 __attribute__((ext_vector_type(8)));
typedef bf16 bf16x4 __attribute__((ext_vector_type(4)));
typedef float f32x4 __attribute__((ext_vector_type(4)));

// monotone float <-> uint encoding for atomicMin on float
__device__ inline unsigned fenc(float f) {
    unsigned u = __float_as_uint(f);
    return (u & 0x80000000u) ? ~u : (u | 0x80000000u);
}
__device__ inline float fdec(unsigned e) {
    unsigned u = (e & 0x80000000u) ? (e & 0x7fffffffu) : ~e;
    return __uint_as_float(u);
}

__device__ __forceinline__ void gload_lds16(const bf16* g, bf16* l) {
    __builtin_amdgcn_global_load_lds(
        (const __attribute__((address_space(1))) unsigned int*)g,
        (__attribute__((address_space(3))) unsigned int*)l, 16, 0, 0);
}

// fp32 -> bf16 conversion (W only: 4 MB, ~2 us)
__global__ void cvt_kernel(const float* __restrict__ in, bf16* __restrict__ out, long n4) {
    long i = (long)blockIdx.x * blockDim.x + threadIdx.x;
    long stride = (long)gridDim.x * blockDim.x;
    for (; i < n4; i += stride) {
        f32x4 v = ((const f32x4*)in)[i];
        bf16x4 h;
        h[0] = (bf16)v[0]; h[1] = (bf16)v[1]; h[2] = (bf16)v[2]; h[3] = (bf16)v[3];
        ((bf16x4*)out)[i] = h;
    }
}

// FINAL (R19, session best: 470.6 us total). 128x128, BK=64, 4 waves,
// 32 KB LDS, conflict-free XOR swizzle, XCD-chunked block swizzle,
// A staged from FP32 x with a full-iteration register prefetch and an
// exact vmcnt FIFO ledger:
//   [B: 4x gload_lds] sched_barrier(0) [cvt va -> swizzled ds_write]
//   [A_PREFETCH(kt+1): 8 loads] barrier-1: vmcnt(8)+lgkm(0) [MFMA]
//   barrier-2: lgkm(0) only (prefetch survives; consumed next iter
//   ~1500 cyc after issue >> 900 cyc HBM latency).
// launch_bounds(256,3) is LOAD-BEARING: the kernel needs ~80 VGPR;
// 3 blocks/CU fits (R19: VGPR 80, WRITE 16 MB, no spill), while
// demanding 4 blocks caps VGPR at 64 and spills va to scratch
// (R20: WRITE 632 MB, GEMM 855 us). 2 blocks under-occupies (R17).
__global__ __launch_bounds__(256, 3)
void gemm_fused(const float* __restrict__ X, const bf16* __restrict__ Wb,
                const float* __restrict__ gnw, const float* __restrict__ gnb,
                unsigned* __restrict__ rowmin) {
    __shared__ __align__(16) bf16 As[128][64];
    __shared__ __align__(16) bf16 Bs[128][64];

    const int tid = threadIdx.x;
    const int wave = tid >> 6, lane = tid & 63;
    const int wr = wave >> 1, wc = wave & 1;   // 2 x 2 wave grid
    const int q = lane >> 4, r = lane & 15;

    // T1: bijective XCD-chunked swizzle (4096 blocks % 8 == 0)
    const int bid = blockIdx.x;
    const int swz = (bid & 7) * 512 + (bid >> 3);
    const int bx = swz & 7, by = swz >> 3;
    const int brow = by * 128, bcol = bx * 128;

    const float* Arowf = X + (size_t)brow * K_DIM;
    const bf16* Brow = Wb + (size_t)bcol * K_DIM;

    f32x4 acc[4][4];
#pragma unroll
    for (int m = 0; m < 4; ++m)
#pragma unroll
        for (int n = 0; n < 4; ++n) acc[m][n] = 0.0f;

    // read-side swizzled granule offsets (bf16 units), per kk half
    const int r7 = r & 7;
    const int ga0 = ((0 + q) ^ r7) * 8;   // kk = 0
    const int ga1 = ((4 + q) ^ r7) * 8;   // kk = 32
    const int arow_l = wr * 64 + r;       // + m*16
    const int brow_l = wc * 64 + r;       // + n*16

    f32x4 va[8];  // single in-flight fp32 A buffer (statically indexed)

#define A_PREFETCH(KT) do {                                                       \
        const int kp = ((KT) & 31) * 64;                                          \
        _Pragma("unroll") for (int j = 0; j < 4; ++j) {                           \
            int gi = j * 256 + tid;                                               \
            int row = gi >> 3, g = gi & 7;                                        \
            const float* src = Arowf + (size_t)row * K_DIM + kp + g * 8;          \
            va[2 * j]     = *(const f32x4*)(src);                                 \
            va[2 * j + 1] = *(const f32x4*)(src + 4);                             \
        }                                                                         \
    } while (0)

#define TILE_ITER(KT) do {                                                        \
        const int k0 = (KT) * 64;                                                 \
        /* B: gload_lds + source-side swizzle (4 loads, MUST be oldest) */        \
        _Pragma("unroll") for (int i = 0; i < 4; ++i) {                           \
            int chunk = i * 256 + tid;                                            \
            int row = chunk >> 3, g = chunk & 7;                                  \
            int gsw = g ^ (row & 7);                                              \
            gload_lds16(Brow + (size_t)row * K_DIM + k0 + gsw * 8,                \
                        &Bs[0][0] + (size_t)(i * 256 + (tid & 192)) * 8);         \
        }                                                                         \
        __builtin_amdgcn_sched_barrier(0);  /* pin: B before A-prefetch */        \
        /* A: convert va (tile KT, loaded last iter) + swizzled ds_write */       \
        _Pragma("unroll") for (int j = 0; j < 4; ++j) {                           \
            int gi = j * 256 + tid;                                               \
            int row = gi >> 3, g = gi & 7;                                        \
            bf16x8 h;                                                             \
            h[0] = (bf16)va[2 * j][0];     h[1] = (bf16)va[2 * j][1];             \
            h[2] = (bf16)va[2 * j][2];     h[3] = (bf16)va[2 * j][3];             \
            h[4] = (bf16)va[2 * j + 1][0]; h[5] = (bf16)va[2 * j + 1][1];         \
            h[6] = (bf16)va[2 * j + 1][2]; h[7] = (bf16)va[2 * j + 1][3];         \
            *(bf16x8*)(&As[0][0] + (size_t)row * 64 +                             \
                       (size_t)(g ^ (row & 7)) * 8) = h;                          \
        }                                                                         \
        /* A-prefetch for tile KT+1 (8 loads, newer than B) */                    \
        A_PREFETCH((KT) + 1);                                                     \
        /* barrier-1: drain exactly B (oldest 4 of 12) + LDS writes */            \
        asm volatile("s_waitcnt vmcnt(8) lgkmcnt(0)" ::: "memory");               \
        __builtin_amdgcn_s_barrier();                                             \
        asm volatile("" ::: "memory");                                            \
        /* MFMA region */                                                         \
        _Pragma("unroll") for (int kk = 0; kk < 2; ++kk) {                        \
            const int ga = kk ? ga1 : ga0;                                        \
            bf16x8 a[4], b[4];                                                    \
            _Pragma("unroll") for (int m = 0; m < 4; ++m)                         \
                a[m] = *(const bf16x8*)(&As[0][0] + (arow_l + m * 16) * 64 + ga); \
            _Pragma("unroll") for (int n = 0; n < 4; ++n)                         \
                b[n] = *(const bf16x8*)(&Bs[0][0] + (brow_l + n * 16) * 64 + ga); \
            _Pragma("unroll") for (int m = 0; m < 4; ++m)                         \
                _Pragma("unroll") for (int n = 0; n < 4; ++n)                     \
                    acc[m][n] = __builtin_amdgcn_mfma_f32_16x16x32_bf16(          \
                        a[m], b[n], acc[m][n], 0, 0, 0);                          \
        }                                                                         \
        /* barrier-2: lgkm only — A-prefetch survives */                          \
        asm volatile("s_waitcnt lgkmcnt(0)" ::: "memory");                        \
        __builtin_amdgcn_s_barrier();                                             \
        asm volatile("" ::: "memory");                                            \
    } while (0)

    // ---- prologue: load tile 0's fp32 A into va ----
    A_PREFETCH(0);

    // ---- main loop: 32 K-tiles ----
    for (int kt = 0; kt < 32; ++kt) {
        TILE_ITER(kt);   // kt=31 prefetches tile 0 (unused)
    }

    // ---- fused epilogue: GroupNorm (group == wave's 64-col span) + row min ----
    float gw[4], gb[4];
#pragma unroll
    for (int n = 0; n < 4; ++n) {
        int col = bcol + wc * 64 + n * 16 + r;
        gw[n] = gnw[col];
        gb[n] = gnb[col];
    }
#pragma unroll
    for (int m = 0; m < 4; ++m) {
#pragma unroll
        for (int j = 0; j < 4; ++j) {
            float s = 0.f, ss = 0.f;
#pragma unroll
            for (int n = 0; n < 4; ++n) {
                float v = acc[m][n][j];
                s += v; ss += v * v;
            }
#pragma unroll
            for (int d = 1; d < 16; d <<= 1) {
                s += __shfl_xor(s, d);
                ss += __shfl_xor(ss, d);
            }
            float mean = s * (1.f / 64.f);
            float var = ss * (1.f / 64.f) - mean * mean;
            float rstd = rsqrtf(var + EPSV);
            float mn = 3.4e38f;
#pragma unroll
            for (int n = 0; n < 4; ++n) {
                float y = (acc[m][n][j] - mean) * rstd * gw[n] + gb[n];
                mn = fminf(mn, y);
            }
#pragma unroll
            for (int d = 1; d < 16; d <<= 1) mn = fminf(mn, __shfl_xor(mn, d));
            if (r == 0)
                atomicMin(&rowmin[brow + wr * 64 + m * 16 + q * 4 + j], fenc(mn));
        }
    }
}

// out[m][n] = dec(rowmin[m]) + bias[n]
__global__ void bcast_kernel(const unsigned* __restrict__ rowmin,
                             const float* __restrict__ bias,
                             float* __restrict__ out) {
    const long total4 = (long)M_DIM * N_DIM / 4;
    long i = (long)blockIdx.x * blockDim.x + threadIdx.x;
    long stride = (long)gridDim.x * blockDim.x;
    for (; i < total4; i += stride) {
        int mrow = (int)(i >> 8);  // N/4 = 256 float4 per row
        int n4 = (int)(i & 255);
        float rm = fdec(rowmin[mrow]);
        f32x4 b = ((const f32x4*)bias)[n4];
        f32x4 o;
        o[0] = rm + b[0]; o[1] = rm + b[1]; o[2] = rm + b[2]; o[3] = rm + b[3];
        ((f32x4*)out)[i] = o;
    }
}

extern "C" void kernel_launch(void* const* d_in, const int* in_sizes, int n_in,
                              void* d_out, int out_size, void* d_ws, size_t ws_size,
                              hipStream_t stream) {
    const float* x = (const float*)d_in[0];
    const float* w = (const float*)d_in[1];
    const float* gnw = (const float*)d_in[2];
    const float* gnb = (const float*)d_in[3];
    const float* bias = (const float*)d_in[4];

    unsigned char* ws = (unsigned char*)d_ws;
    unsigned* rowmin = (unsigned*)ws;                          // 256 KB
    bf16* wb = (bf16*)(ws + (size_t)M_DIM * 4);                // 4 MB

    (void)hipMemsetAsync(rowmin, 0xFF, (size_t)M_DIM * 4, stream);  // +inf in encoding
    cvt_kernel<<<512, 256, 0, stream>>>(w, wb, (long)N_DIM * K_DIM / 4);

    gemm_fused<<<dim3(4096), 256, 0, stream>>>(x, wb, gnw, gnb, rowmin);

    bcast_kernel<<<2048, 256, 0, stream>>>(rowmin, bias, (float*)d_out);
}